// Round 7
// baseline (640.164 us; speedup 1.0000x reference)
//
#include <hip/hip_runtime.h>
#include <hip/hip_bf16.h>
#include <math.h>

#define NTOK   8192   // B*T = 4*2048
#define DM     1024   // d_model
#define DH     4096   // hidden
#define NE     8      // experts
#define CAP    17408  // max gathered rows: 2*NTOK + 8*127, rounded up to 128
#define CAPT   (CAP/128)   // 136 row-tiles

typedef __bf16 bf16;
typedef __bf16 bf16x4 __attribute__((ext_vector_type(4)));
typedef __bf16 bf16x8 __attribute__((ext_vector_type(8)));
typedef float  f32x4  __attribute__((ext_vector_type(4)));

__device__ __forceinline__ void gload16(const void* g, void* l) {
  __builtin_amdgcn_global_load_lds(
      (const __attribute__((address_space(1))) void*)g,
      (__attribute__((address_space(3))) void*)l, 16, 0, 0);
}
// NT (CPol bit1) variant: streaming operand, evict-first in L2 so the
// reused B panels stay resident.
__device__ __forceinline__ void gload16nt(const void* g, void* l) {
  __builtin_amdgcn_global_load_lds(
      (const __attribute__((address_space(1))) void*)g,
      (__attribute__((address_space(3))) void*)l, 16, 0, 2);
}

// fast GELU (tanh form)
__device__ __forceinline__ float gelu_f(float v) {
  float u = v * v * v;
  float t = 1.5957691216f * v + 0.0713548162726f * u;
  float e = __expf(-t);
  return v * __builtin_amdgcn_rcpf(1.0f + e);
}

// ------------- fp32 [E][R][C] -> bf16 [E][C][R] tiled transpose -------------
__global__ void transpose_convert_kernel(const float* __restrict__ src,
                                         bf16* __restrict__ dst, int R, int C) {
  __shared__ bf16 tile[64][66];
  int e = blockIdx.z;
  src += (size_t)e * R * C;
  dst += (size_t)e * R * C;
  int c0 = blockIdx.x * 64;
  int r0 = blockIdx.y * 64;
  int lr = threadIdx.x >> 6;   // 0..3
  int lc = threadIdx.x & 63;
#pragma unroll
  for (int i = 0; i < 16; i++) {
    int r = lr + i * 4;
    float v = __builtin_nontemporal_load(&src[(size_t)(r0 + r) * C + c0 + lc]);
    tile[r][lc] = (bf16)v;
  }
  __syncthreads();
#pragma unroll
  for (int i = 0; i < 16; i++) {
    int r = lr + i * 4;  // row of dst block (= src col)
    bf16 tv = tile[lc][r];
    __builtin_nontemporal_store(*(const short*)&tv,
                                (short*)&dst[(size_t)(c0 + r) * R + r0 + lc]);
  }
}

// -- gating fused with x->bf16 convert: logits -> top2 -> softmax weights --
__global__ void gating_kernel(const float* __restrict__ x,
                              const float* __restrict__ gw,
                              const float* __restrict__ gb,
                              bf16* __restrict__ xb,
                              int* __restrict__ assignE,
                              float2* __restrict__ assignW) {
  int wave = threadIdx.x >> 6, lane = threadIdx.x & 63;
  int t = blockIdx.x * 4 + wave;
  const float* xr = x + (size_t)t * DM;
  // each lane owns 16 contiguous d: [lane*16, lane*16+16)
  float4 xv[4];
  const float4* xr4 = reinterpret_cast<const float4*>(xr) + lane * 4;
#pragma unroll
  for (int i = 0; i < 4; i++) xv[i] = xr4[i];
  // convert + store bf16 x
#pragma unroll
  for (int i = 0; i < 2; i++) {
    float4 a = xv[2 * i], b = xv[2 * i + 1];
    bf16x8 o;
    o[0] = (bf16)a.x; o[1] = (bf16)a.y; o[2] = (bf16)a.z; o[3] = (bf16)a.w;
    o[4] = (bf16)b.x; o[5] = (bf16)b.y; o[6] = (bf16)b.z; o[7] = (bf16)b.w;
    reinterpret_cast<bf16x8*>(xb + (size_t)t * DM)[lane * 2 + i] = o;
  }
  // gate logits
  float acc[8];
#pragma unroll
  for (int e = 0; e < 8; e++) acc[e] = 0.f;
  int d0 = lane * 16;
#pragma unroll
  for (int j = 0; j < 16; j++) {
    float xvj = reinterpret_cast<const float*>(xv)[j];
    const float4* g = reinterpret_cast<const float4*>(gw + (size_t)(d0 + j) * 8);
    float4 g0 = g[0], g1 = g[1];
    acc[0] += xvj * g0.x; acc[1] += xvj * g0.y; acc[2] += xvj * g0.z; acc[3] += xvj * g0.w;
    acc[4] += xvj * g1.x; acc[5] += xvj * g1.y; acc[6] += xvj * g1.z; acc[7] += xvj * g1.w;
  }
#pragma unroll
  for (int off = 32; off > 0; off >>= 1)
#pragma unroll
    for (int e = 0; e < 8; e++) acc[e] += __shfl_xor(acc[e], off, 64);
  if (lane == 0) {
    float v[8];
#pragma unroll
    for (int e = 0; e < 8; e++) v[e] = acc[e] + gb[e];
    int i0 = 0; float v0 = v[0];
#pragma unroll
    for (int e = 1; e < 8; e++) if (v[e] > v0) { v0 = v[e]; i0 = e; }
    int i1 = -1; float v1 = -1e30f;
#pragma unroll
    for (int e = 0; e < 8; e++) if (e != i0 && v[e] > v1) { v1 = v[e]; i1 = e; }
    float p1 = expf(v1 - v0);
    float den = 1.f + p1;
    assignE[t] = i0 | (i1 << 8);
    assignW[t] = make_float2(1.f / den, p1 / den);
  }
}

// ---- router (single block): histogram -> 128-aligned offsets -> LUT -> scatter ----
__global__ void router_kernel(const int* __restrict__ assignE,
                              const float2* __restrict__ assignW,
                              int* __restrict__ rowTok,
                              float* __restrict__ rowW,
                              int2* __restrict__ tokRow,
                              int* __restrict__ tileExpert) {
  __shared__ int cnt[NE], off[NE + 1], cur[NE];
  int tid = threadIdx.x;
  if (tid < NE) cnt[tid] = 0;
  __syncthreads();
  for (int t = tid; t < NTOK; t += 256) {
    int ae = assignE[t];
    atomicAdd(&cnt[ae & 255], 1);
    atomicAdd(&cnt[(ae >> 8) & 255], 1);
  }
  __syncthreads();
  if (tid == 0) {
    int o = 0;
    for (int e = 0; e < NE; e++) { off[e] = o; o += ((cnt[e] + 127) >> 7) << 7; }
    off[NE] = o;
  }
  __syncthreads();
  if (tid < NE) cur[tid] = 0;
  for (int i = tid; i < CAPT; i += 256) {
    int r = i * 128, ex = -1;
#pragma unroll
    for (int e = 0; e < NE; e++)
      if (r >= off[e] && r < off[e + 1]) ex = e;
    tileExpert[i] = ex;
  }
  for (int i = tid; i < CAP; i += 256) { rowTok[i] = -1; rowW[i] = 0.f; }
  __syncthreads();
  for (int t = tid; t < NTOK; t += 256) {
    int ae = assignE[t];
    float2 aw = assignW[t];
    int e0 = ae & 255, e1 = (ae >> 8) & 255;
    int p0 = off[e0] + atomicAdd(&cur[e0], 1);
    rowTok[p0] = t; rowW[p0] = aw.x;
    int p1 = off[e1] + atomicAdd(&cur[e1], 1);
    rowTok[p1] = t; rowW[p1] = aw.y;
    tokRow[t] = make_int2(p0, p1);
  }
}

// ---------------- grouped bf16 MFMA GEMM over expert segments ----------------
// Double-buffered K-loop: STAGE(next) issued before compute(cur); one
// syncthreads per K-step. A-operand of GEMM2 loaded NT (streaming); epilogue
// stores NT (written once) so B panels keep their L2 residency.
// EPI==0: A gathered via rowTok; Hout[r,n] = gelu(C + bias[n])  (bf16)
// EPI==1: A direct; Y[r][n] = rowW[r] * (C + bias[n])  (fp32, linear)
template <int EPI>
__global__ __launch_bounds__(256) void moe_gemm_kernel(
    const bf16* __restrict__ A, const bf16* __restrict__ Bt,
    const float* __restrict__ bias, bf16* __restrict__ Hout,
    float* __restrict__ Y,
    const int* __restrict__ rowTok, const float* __restrict__ rowW,
    const int* __restrict__ tileExpert,
    int N, int K) {
  constexpr int BM = 128, BN = 128, BK = 64;
  __shared__ __align__(16) bf16 As0[BM * BK];
  __shared__ __align__(16) bf16 Bs0[BN * BK];
  __shared__ __align__(16) bf16 As1[BM * BK];
  __shared__ __align__(16) bf16 Bs1[BN * BK];
  const int tid = threadIdx.x;
  const int wave = tid >> 6, lane = tid & 63;
  const int nbn = N / BN;
  const int bid = (int)blockIdx.x;
  // natural order: XCD = bid % 8 = fixed column stripe -> B-panel L2 affinity;
  // all XCDs stream the same A row-panel through L3 together.
  const int rt = bid / nbn;
  const int e = tileExpert[rt];
  if (e < 0) return;
  const int bm0 = rt * BM;
  const int bn0 = (bid % nbn) * BN;
  const int wm = (wave >> 1) * 64, wn = (wave & 1) * 64;
  const bf16* Be = Bt + (size_t)e * N * K;
  const float* be = bias + (size_t)e * N;

  f32x4 acc[4][4];
#pragma unroll
  for (int m = 0; m < 4; m++)
#pragma unroll
    for (int n = 0; n < 4; n++)
#pragma unroll
      for (int j = 0; j < 4; j++) acc[m][n][j] = 0.f;

  const int srow = lane >> 3;            // 0..7 within an 8-row chunk
  const int scolb = (lane & 7) << 4;     // byte col 0..112

  // hoist per-thread row base pointers (rows fixed across K-loop)
  const char* gaBase[4];
  const char* gbBase[4];
#pragma unroll
  for (int it = 0; it < 4; it++) {
    int chunk = it * 4 + wave;
    int row = chunk * 8 + srow;
    int csw = scolb ^ ((row & 7) << 4);  // pre-swizzled source (rule #21)
    size_t arow;
    if constexpr (EPI == 0) {
      int tok = rowTok[bm0 + row];
      arow = (size_t)(tok < 0 ? 0 : tok);
    } else {
      arow = (size_t)(bm0 + row);
    }
    gaBase[it] = (const char*)A + arow * (size_t)K * 2 + csw;
    gbBase[it] = (const char*)Be + ((size_t)(bn0 + row)) * K * 2 + csw;
  }

  auto STAGE = [&](int kt, bf16* dstA, bf16* dstB) {
#pragma unroll
    for (int it = 0; it < 4; it++) {
      int chunk = it * 4 + wave;
      if constexpr (EPI == 1)
        gload16nt(gaBase[it] + (size_t)kt * 2, (char*)dstA + chunk * 1024);
      else
        gload16(gaBase[it] + (size_t)kt * 2, (char*)dstA + chunk * 1024);
      gload16(gbBase[it] + (size_t)kt * 2, (char*)dstB + chunk * 1024);
    }
  };

  auto COMPUTE = [&](const bf16* sA, const bf16* sB) {
#pragma unroll
    for (int kk = 0; kk < 2; kk++) {
      const int kb = kk * 64 + ((lane >> 4) << 4);  // byte offset of k in row
      bf16x8 af[4], bfv[4];
#pragma unroll
      for (int m = 0; m < 4; m++) {
        int r = wm + m * 16 + (lane & 15);
        af[m] = *(const bf16x8*)((const char*)sA + r * 128 + (kb ^ ((r & 7) << 4)));
      }
#pragma unroll
      for (int n = 0; n < 4; n++) {
        int r = wn + n * 16 + (lane & 15);
        bfv[n] = *(const bf16x8*)((const char*)sB + r * 128 + (kb ^ ((r & 7) << 4)));
      }
#pragma unroll
      for (int m = 0; m < 4; m++)
#pragma unroll
        for (int n = 0; n < 4; n++)
          acc[m][n] = __builtin_amdgcn_mfma_f32_16x16x32_bf16(af[m], bfv[n], acc[m][n], 0, 0, 0);
    }
  };

  // prologue: fill buffer 0
  STAGE(0, As0, Bs0);
  __syncthreads();                       // vmcnt(0) + barrier: buf0 ready
  // main loop: 2 K-steps per iteration, static buffer references
  for (int kt = 0; kt < K; kt += 2 * BK) {
    if (kt + BK < K) STAGE(kt + BK, As1, Bs1);   // prefetch into buf1
    COMPUTE(As0, Bs0);
    __syncthreads();                     // buf1 ready; buf0 reads done
    if (kt + 2 * BK < K) STAGE(kt + 2 * BK, As0, Bs0);  // prefetch into buf0
    COMPUTE(As1, Bs1);
    __syncthreads();                     // buf0 ready; buf1 reads done
  }

  const int rb = bm0 + wm + ((lane >> 4) << 2);
  const int cb = bn0 + wn + (lane & 15);
  if constexpr (EPI == 0) {
#pragma unroll
    for (int m = 0; m < 4; m++)
#pragma unroll
      for (int n = 0; n < 4; n++) {
        int c = cb + n * 16;
        float bv = be[c];
#pragma unroll
        for (int j = 0; j < 4; j++) {
          int r = rb + m * 16 + j;
          bf16 hv = (bf16)gelu_f(acc[m][n][j] + bv);
          __builtin_nontemporal_store(*(const short*)&hv,
                                      (short*)&Hout[(size_t)r * N + c]);
        }
      }
  } else {
#pragma unroll
    for (int m = 0; m < 4; m++) {
#pragma unroll
      for (int j = 0; j < 4; j++) {
        int r = rb + m * 16 + j;
        float w = rowW[r];
        float* yrow = Y + (size_t)r * DM;
#pragma unroll
        for (int n = 0; n < 4; n++) {
          int c = cb + n * 16;
          __builtin_nontemporal_store(w * (acc[m][n][j] + be[c]), &yrow[c]);
        }
      }
    }
  }
}

// ---------------- combine: out[t] = Y[p0] + Y[p1] ----------------
__global__ void combine_kernel(const float* __restrict__ Y,
                               const int2* __restrict__ tokRow,
                               float* __restrict__ out) {
  int wave = threadIdx.x >> 6, lane = threadIdx.x & 63;
  int t = blockIdx.x * 4 + wave;
  int2 pr = tokRow[t];
  const f32x4* a = (const f32x4*)(Y + (size_t)pr.x * DM);
  const f32x4* b = (const f32x4*)(Y + (size_t)pr.y * DM);
  f32x4* o = (f32x4*)(out + (size_t)t * DM);
#pragma unroll
  for (int i = 0; i < 4; i++) {
    int idx = lane + i * 64;
    f32x4 s = a[idx] + b[idx];
    __builtin_nontemporal_store(s, &o[idx]);
  }
}

extern "C" void kernel_launch(void* const* d_in, const int* in_sizes, int n_in,
                              void* d_out, int out_size, void* d_ws, size_t ws_size,
                              hipStream_t stream) {
  const float* x  = (const float*)d_in[0];
  const float* gw = (const float*)d_in[1];
  const float* gb = (const float*)d_in[2];
  const float* w1 = (const float*)d_in[3];
  const float* b1 = (const float*)d_in[4];
  const float* w2 = (const float*)d_in[5];
  const float* b2 = (const float*)d_in[6];
  float* out = (float*)d_out;

  char* p = (char*)d_ws;
  bf16* xb   = (bf16*)p;  p += (size_t)NTOK * DM * 2;      // 16.8 MB (dead after GEMM1)
  bf16* w1t  = (bf16*)p;  p += (size_t)NE * DM * DH * 2;   // 67 MB   (dead after GEMM1)
  bf16* Hg   = (bf16*)p;  p += (size_t)CAP * DH * 2;       // 142.6 MB
  bf16* w2t  = (bf16*)p;  p += (size_t)NE * DM * DH * 2;   // 67 MB  [E][D][H]
  int*   assignE = (int*)p;     p += (size_t)NTOK * 4;
  float2* assignW = (float2*)p; p += (size_t)NTOK * 8;
  int*   rowTok = (int*)p;      p += (size_t)CAP * 4;
  float* rowW   = (float*)p;    p += (size_t)CAP * 4;
  int2*  tokRow = (int2*)p;     p += (size_t)NTOK * 8;
  int*   tileExpert = (int*)p;  p += (size_t)CAPT * 4;
  // Y aliases xb+w1t (71.3 MB <= 83.8 MB; both dead once GEMM2 runs)
  float* Y = (float*)d_ws;

  // w1 [E][DM][DH] -> w1t [E][DH][DM]
  transpose_convert_kernel<<<dim3(DH / 64, DM / 64, NE), 256, 0, stream>>>(w1, w1t, DM, DH);
  // w2 [E][DH][DM] -> w2t [E][DM][DH]
  transpose_convert_kernel<<<dim3(DM / 64, DH / 64, NE), 256, 0, stream>>>(w2, w2t, DH, DM);
  gating_kernel<<<NTOK / 4, 256, 0, stream>>>(x, gw, gb, xb, assignE, assignW);
  router_kernel<<<1, 256, 0, stream>>>(assignE, assignW, rowTok, rowW, tokRow, tileExpert);

  // GEMM1: gathered x @ w1^T -> gelu -> Hg   [CAP x DH]
  moe_gemm_kernel<0><<<CAPT * (DH / 128), 256, 0, stream>>>(
      xb, w1t, b1, Hg, nullptr, rowTok, nullptr, tileExpert, DH, DM);
  // GEMM2: Hg @ w2^T -> Y[r] = w*(y+b2)  (linear, gathered-row space)
  moe_gemm_kernel<1><<<CAPT * (DM / 128), 256, 0, stream>>>(
      Hg, w2t, b2, nullptr, Y, rowTok, rowW, tileExpert, DM, DH);

  combine_kernel<<<NTOK / 4, 256, 0, stream>>>(Y, tokRow, out);
}

// Round 8
// 582.238 us; speedup vs baseline: 1.0995x; 1.0995x over previous
//
#include <hip/hip_runtime.h>
#include <hip/hip_bf16.h>
#include <math.h>

#define NTOK   8192   // B*T = 4*2048
#define DM     1024   // d_model
#define DH     4096   // hidden
#define NE     8      // experts
#define CAP    17408  // max gathered rows: 2*NTOK + 8*127, rounded up to 128
#define CAPT   (CAP/128)   // 136 row-tiles

typedef __bf16 bf16;
typedef __bf16 bf16x4 __attribute__((ext_vector_type(4)));
typedef __bf16 bf16x8 __attribute__((ext_vector_type(8)));
typedef float  f32x4  __attribute__((ext_vector_type(4)));

__device__ __forceinline__ void gload16(const void* g, void* l) {
  __builtin_amdgcn_global_load_lds(
      (const __attribute__((address_space(1))) void*)g,
      (__attribute__((address_space(3))) void*)l, 16, 0, 0);
}

// fast GELU (tanh form)
__device__ __forceinline__ float gelu_f(float v) {
  float u = v * v * v;
  float t = 1.5957691216f * v + 0.0713548162726f * u;
  float e = __expf(-t);
  return v * __builtin_amdgcn_rcpf(1.0f + e);
}

// ------------- fp32 [E][R][C] -> bf16 [E][C][R] tiled transpose -------------
__global__ void transpose_convert_kernel(const float* __restrict__ src,
                                         bf16* __restrict__ dst, int R, int C) {
  __shared__ bf16 tile[64][66];
  int e = blockIdx.z;
  src += (size_t)e * R * C;
  dst += (size_t)e * R * C;
  int c0 = blockIdx.x * 64;
  int r0 = blockIdx.y * 64;
  int lr = threadIdx.x >> 6;   // 0..3
  int lc = threadIdx.x & 63;
#pragma unroll
  for (int i = 0; i < 16; i++) {
    int r = lr + i * 4;
    tile[r][lc] = (bf16)src[(size_t)(r0 + r) * C + c0 + lc];
  }
  __syncthreads();
#pragma unroll
  for (int i = 0; i < 16; i++) {
    int r = lr + i * 4;  // row of dst block (= src col)
    dst[(size_t)(c0 + r) * R + r0 + lc] = tile[lc][r];
  }
}

// -- gating fused with x->bf16 convert: logits -> top2 -> softmax weights --
__global__ void gating_kernel(const float* __restrict__ x,
                              const float* __restrict__ gw,
                              const float* __restrict__ gb,
                              bf16* __restrict__ xb,
                              int* __restrict__ assignE,
                              float2* __restrict__ assignW) {
  int wave = threadIdx.x >> 6, lane = threadIdx.x & 63;
  int t = blockIdx.x * 4 + wave;
  const float* xr = x + (size_t)t * DM;
  // each lane owns 16 contiguous d: [lane*16, lane*16+16)
  float4 xv[4];
  const float4* xr4 = reinterpret_cast<const float4*>(xr) + lane * 4;
#pragma unroll
  for (int i = 0; i < 4; i++) xv[i] = xr4[i];
  // convert + store bf16 x
#pragma unroll
  for (int i = 0; i < 2; i++) {
    float4 a = xv[2 * i], b = xv[2 * i + 1];
    bf16x8 o;
    o[0] = (bf16)a.x; o[1] = (bf16)a.y; o[2] = (bf16)a.z; o[3] = (bf16)a.w;
    o[4] = (bf16)b.x; o[5] = (bf16)b.y; o[6] = (bf16)b.z; o[7] = (bf16)b.w;
    reinterpret_cast<bf16x8*>(xb + (size_t)t * DM)[lane * 2 + i] = o;
  }
  // gate logits
  float acc[8];
#pragma unroll
  for (int e = 0; e < 8; e++) acc[e] = 0.f;
  int d0 = lane * 16;
#pragma unroll
  for (int j = 0; j < 16; j++) {
    float xvj = reinterpret_cast<const float*>(xv)[j];
    const float4* g = reinterpret_cast<const float4*>(gw + (size_t)(d0 + j) * 8);
    float4 g0 = g[0], g1 = g[1];
    acc[0] += xvj * g0.x; acc[1] += xvj * g0.y; acc[2] += xvj * g0.z; acc[3] += xvj * g0.w;
    acc[4] += xvj * g1.x; acc[5] += xvj * g1.y; acc[6] += xvj * g1.z; acc[7] += xvj * g1.w;
  }
#pragma unroll
  for (int off = 32; off > 0; off >>= 1)
#pragma unroll
    for (int e = 0; e < 8; e++) acc[e] += __shfl_xor(acc[e], off, 64);
  if (lane == 0) {
    float v[8];
#pragma unroll
    for (int e = 0; e < 8; e++) v[e] = acc[e] + gb[e];
    int i0 = 0; float v0 = v[0];
#pragma unroll
    for (int e = 1; e < 8; e++) if (v[e] > v0) { v0 = v[e]; i0 = e; }
    int i1 = -1; float v1 = -1e30f;
#pragma unroll
    for (int e = 0; e < 8; e++) if (e != i0 && v[e] > v1) { v1 = v[e]; i1 = e; }
    float p1 = expf(v1 - v0);
    float den = 1.f + p1;
    assignE[t] = i0 | (i1 << 8);
    assignW[t] = make_float2(1.f / den, p1 / den);
  }
}

// ---- router (single block): histogram -> 128-aligned offsets -> LUT -> scatter ----
__global__ void router_kernel(const int* __restrict__ assignE,
                              const float2* __restrict__ assignW,
                              int* __restrict__ rowTok,
                              float* __restrict__ rowW,
                              int2* __restrict__ tokRow,
                              int* __restrict__ tileExpert) {
  __shared__ int cnt[NE], off[NE + 1], cur[NE];
  int tid = threadIdx.x;
  if (tid < NE) cnt[tid] = 0;
  __syncthreads();
  for (int t = tid; t < NTOK; t += 256) {
    int ae = assignE[t];
    atomicAdd(&cnt[ae & 255], 1);
    atomicAdd(&cnt[(ae >> 8) & 255], 1);
  }
  __syncthreads();
  if (tid == 0) {
    int o = 0;
    for (int e = 0; e < NE; e++) { off[e] = o; o += ((cnt[e] + 127) >> 7) << 7; }
    off[NE] = o;
  }
  __syncthreads();
  if (tid < NE) cur[tid] = 0;
  for (int i = tid; i < CAPT; i += 256) {
    int r = i * 128, ex = -1;
#pragma unroll
    for (int e = 0; e < NE; e++)
      if (r >= off[e] && r < off[e + 1]) ex = e;
    tileExpert[i] = ex;
  }
  for (int i = tid; i < CAP; i += 256) { rowTok[i] = -1; rowW[i] = 0.f; }
  __syncthreads();
  for (int t = tid; t < NTOK; t += 256) {
    int ae = assignE[t];
    float2 aw = assignW[t];
    int e0 = ae & 255, e1 = (ae >> 8) & 255;
    int p0 = off[e0] + atomicAdd(&cur[e0], 1);
    rowTok[p0] = t; rowW[p0] = aw.x;
    int p1 = off[e1] + atomicAdd(&cur[e1], 1);
    rowTok[p1] = t; rowW[p1] = aw.y;
    tokRow[t] = make_int2(p0, p1);
  }
}

// ---------------- grouped bf16 MFMA GEMM over expert segments ----------------
// T4 counted-vmcnt pipeline, prefetch depth 2 on a 2-buffer ring:
//   COMPUTE(P); s_barrier; STAGE(t+2 -> P); s_waitcnt vmcnt(8); s_barrier
// Ledger (8 gload_lds per thread per K-step): steady outstanding after STAGE
// = 16 -> vmcnt(8) retires exactly the next buffer's 8; vmcnt(0) only on the
// final transition. No full drain inside the main loop (T4, m218/m201).
// EPI==0: A gathered via rowTok; Hout[r,n] = gelu(C + bias[n])  (bf16)
// EPI==1: A direct; Y[r][n] = rowW[r] * (C + bias[n])  (fp32, linear)
template <int EPI>
__global__ __launch_bounds__(256) void moe_gemm_kernel(
    const bf16* __restrict__ A, const bf16* __restrict__ Bt,
    const float* __restrict__ bias, bf16* __restrict__ Hout,
    float* __restrict__ Y,
    const int* __restrict__ rowTok, const float* __restrict__ rowW,
    const int* __restrict__ tileExpert,
    int N, int K) {
  constexpr int BM = 128, BN = 128, BK = 64;
  __shared__ __align__(16) bf16 As0[BM * BK];
  __shared__ __align__(16) bf16 Bs0[BN * BK];
  __shared__ __align__(16) bf16 As1[BM * BK];
  __shared__ __align__(16) bf16 Bs1[BN * BK];
  const int tid = threadIdx.x;
  const int wave = tid >> 6, lane = tid & 63;
  const int nbn = N / BN;
  const int bid = (int)blockIdx.x;
  // natural order: XCD = bid % 8 = fixed column stripe -> B-panel L2 affinity
  const int rt = bid / nbn;
  const int e = tileExpert[rt];
  if (e < 0) return;
  const int bm0 = rt * BM;
  const int bn0 = (bid % nbn) * BN;
  const int wm = (wave >> 1) * 64, wn = (wave & 1) * 64;
  const bf16* Be = Bt + (size_t)e * N * K;
  const float* be = bias + (size_t)e * N;

  f32x4 acc[4][4];
#pragma unroll
  for (int m = 0; m < 4; m++)
#pragma unroll
    for (int n = 0; n < 4; n++)
#pragma unroll
      for (int j = 0; j < 4; j++) acc[m][n][j] = 0.f;

  const int srow = lane >> 3;            // 0..7 within an 8-row chunk
  const int scolb = (lane & 7) << 4;     // byte col 0..112

  // hoist per-thread row base pointers (rows fixed across K-loop)
  const char* gaBase[4];
  const char* gbBase[4];
#pragma unroll
  for (int it = 0; it < 4; it++) {
    int chunk = it * 4 + wave;
    int row = chunk * 8 + srow;
    int csw = scolb ^ ((row & 7) << 4);  // pre-swizzled source (rule #21)
    size_t arow;
    if constexpr (EPI == 0) {
      int tok = rowTok[bm0 + row];
      arow = (size_t)(tok < 0 ? 0 : tok);
    } else {
      arow = (size_t)(bm0 + row);
    }
    gaBase[it] = (const char*)A + arow * (size_t)K * 2 + csw;
    gbBase[it] = (const char*)Be + ((size_t)(bn0 + row)) * K * 2 + csw;
  }

  auto STAGE = [&](int kt, bf16* dstA, bf16* dstB) {
#pragma unroll
    for (int it = 0; it < 4; it++) {
      int chunk = it * 4 + wave;
      gload16(gaBase[it] + (size_t)kt * 2, (char*)dstA + chunk * 1024);
      gload16(gbBase[it] + (size_t)kt * 2, (char*)dstB + chunk * 1024);
    }
  };

  auto COMPUTE = [&](const bf16* sA, const bf16* sB) {
#pragma unroll
    for (int kk = 0; kk < 2; kk++) {
      const int kb = kk * 64 + ((lane >> 4) << 4);  // byte offset of k in row
      bf16x8 af[4], bfv[4];
#pragma unroll
      for (int m = 0; m < 4; m++) {
        int r = wm + m * 16 + (lane & 15);
        af[m] = *(const bf16x8*)((const char*)sA + r * 128 + (kb ^ ((r & 7) << 4)));
      }
#pragma unroll
      for (int n = 0; n < 4; n++) {
        int r = wn + n * 16 + (lane & 15);
        bfv[n] = *(const bf16x8*)((const char*)sB + r * 128 + (kb ^ ((r & 7) << 4)));
      }
#pragma unroll
      for (int m = 0; m < 4; m++)
#pragma unroll
        for (int n = 0; n < 4; n++)
          acc[m][n] = __builtin_amdgcn_mfma_f32_16x16x32_bf16(af[m], bfv[n], acc[m][n], 0, 0, 0);
    }
  };

#define BAR()    __builtin_amdgcn_s_barrier()
#define VMCNT8() asm volatile("s_waitcnt vmcnt(8)" ::: "memory")
#define VMCNT0() asm volatile("s_waitcnt vmcnt(0)" ::: "memory")

  const int NT = K / BK;                 // 16 or 64 (even)
  // prologue: fill both buffers, wait only for buf0 (8 of 16 retire)
  STAGE(0, As0, Bs0);
  STAGE(BK, As1, Bs1);
  VMCNT8();
  BAR();
  for (int t = 0; t < NT; t += 2) {
    // ---- even step: compute buf0 ----
    COMPUTE(As0, Bs0);
    BAR();                               // all waves done reading buf0
    if (t + 2 < NT) {
      STAGE((t + 2) * BK, As0, Bs0);     // refill buf0 (16 outstanding)
      VMCNT8();                          // buf1's 8 landed
    } else {
      VMCNT0();                          // penultimate: buf1 landed
    }
    BAR();
    // ---- odd step: compute buf1 ----
    COMPUTE(As1, Bs1);
    if (t + 2 < NT) {
      BAR();                             // all waves done reading buf1
      if (t + 3 < NT) {
        STAGE((t + 3) * BK, As1, Bs1);   // refill buf1
        VMCNT8();                        // buf0's 8 landed
      } else {
        VMCNT0();
      }
      BAR();
    }
  }
#undef BAR
#undef VMCNT8
#undef VMCNT0

  const int rb = bm0 + wm + ((lane >> 4) << 2);
  const int cb = bn0 + wn + (lane & 15);
  if constexpr (EPI == 0) {
#pragma unroll
    for (int m = 0; m < 4; m++)
#pragma unroll
      for (int n = 0; n < 4; n++) {
        int c = cb + n * 16;
        float bv = be[c];
#pragma unroll
        for (int j = 0; j < 4; j++) {
          int r = rb + m * 16 + j;
          Hout[(size_t)r * N + c] = (bf16)gelu_f(acc[m][n][j] + bv);
        }
      }
  } else {
#pragma unroll
    for (int m = 0; m < 4; m++) {
#pragma unroll
      for (int j = 0; j < 4; j++) {
        int r = rb + m * 16 + j;
        float w = rowW[r];
        float* yrow = Y + (size_t)r * DM;
#pragma unroll
        for (int n = 0; n < 4; n++) {
          int c = cb + n * 16;
          yrow[c] = w * (acc[m][n][j] + be[c]);
        }
      }
    }
  }
}

// ---------------- combine: out[t] = Y[p0] + Y[p1] ----------------
__global__ void combine_kernel(const float* __restrict__ Y,
                               const int2* __restrict__ tokRow,
                               float* __restrict__ out) {
  int wave = threadIdx.x >> 6, lane = threadIdx.x & 63;
  int t = blockIdx.x * 4 + wave;
  int2 pr = tokRow[t];
  const float4* a = (const float4*)(Y + (size_t)pr.x * DM);
  const float4* b = (const float4*)(Y + (size_t)pr.y * DM);
  float4* o = (float4*)(out + (size_t)t * DM);
#pragma unroll
  for (int i = 0; i < 4; i++) {
    int idx = lane + i * 64;
    float4 u = a[idx], v = b[idx];
    o[idx] = make_float4(u.x + v.x, u.y + v.y, u.z + v.z, u.w + v.w);
  }
}

extern "C" void kernel_launch(void* const* d_in, const int* in_sizes, int n_in,
                              void* d_out, int out_size, void* d_ws, size_t ws_size,
                              hipStream_t stream) {
  const float* x  = (const float*)d_in[0];
  const float* gw = (const float*)d_in[1];
  const float* gb = (const float*)d_in[2];
  const float* w1 = (const float*)d_in[3];
  const float* b1 = (const float*)d_in[4];
  const float* w2 = (const float*)d_in[5];
  const float* b2 = (const float*)d_in[6];
  float* out = (float*)d_out;

  char* p = (char*)d_ws;
  bf16* xb   = (bf16*)p;  p += (size_t)NTOK * DM * 2;      // 16.8 MB (dead after GEMM1)
  bf16* w1t  = (bf16*)p;  p += (size_t)NE * DM * DH * 2;   // 67 MB   (dead after GEMM1)
  bf16* Hg   = (bf16*)p;  p += (size_t)CAP * DH * 2;       // 142.6 MB
  bf16* w2t  = (bf16*)p;  p += (size_t)NE * DM * DH * 2;   // 67 MB  [E][D][H]
  int*   assignE = (int*)p;     p += (size_t)NTOK * 4;
  float2* assignW = (float2*)p; p += (size_t)NTOK * 8;
  int*   rowTok = (int*)p;      p += (size_t)CAP * 4;
  float* rowW   = (float*)p;    p += (size_t)CAP * 4;
  int2*  tokRow = (int2*)p;     p += (size_t)NTOK * 8;
  int*   tileExpert = (int*)p;  p += (size_t)CAPT * 4;
  // Y aliases xb+w1t (71.3 MB <= 83.8 MB; both dead once GEMM2 runs)
  float* Y = (float*)d_ws;

  // w1 [E][DM][DH] -> w1t [E][DH][DM]
  transpose_convert_kernel<<<dim3(DH / 64, DM / 64, NE), 256, 0, stream>>>(w1, w1t, DM, DH);
  // w2 [E][DH][DM] -> w2t [E][DM][DH]
  transpose_convert_kernel<<<dim3(DM / 64, DH / 64, NE), 256, 0, stream>>>(w2, w2t, DH, DM);
  gating_kernel<<<NTOK / 4, 256, 0, stream>>>(x, gw, gb, xb, assignE, assignW);
  router_kernel<<<1, 256, 0, stream>>>(assignE, assignW, rowTok, rowW, tokRow, tileExpert);

  // GEMM1: gathered x @ w1^T -> gelu -> Hg   [CAP x DH]
  moe_gemm_kernel<0><<<CAPT * (DH / 128), 256, 0, stream>>>(
      xb, w1t, b1, Hg, nullptr, rowTok, nullptr, tileExpert, DH, DM);
  // GEMM2: Hg @ w2^T -> Y[r] = w*(y+b2)  (linear, gathered-row space)
  moe_gemm_kernel<1><<<CAPT * (DM / 128), 256, 0, stream>>>(
      Hg, w2t, b2, nullptr, Y, rowTok, rowW, tileExpert, DM, DH);

  combine_kernel<<<NTOK / 4, 256, 0, stream>>>(Y, tokRow, out);
}

// Round 9
// 568.352 us; speedup vs baseline: 1.1264x; 1.0244x over previous
//
#include <hip/hip_runtime.h>
#include <hip/hip_bf16.h>
#include <math.h>

#define NTOK   8192   // B*T = 4*2048
#define DM     1024   // d_model
#define DH     4096   // hidden
#define NE     8      // experts
#define CAP    17408  // max gathered rows: 2*NTOK + 8*127, rounded up to 128
#define CAPT   (CAP/128)   // 136 row-tiles

typedef __bf16 bf16;
typedef __bf16 bf16x4 __attribute__((ext_vector_type(4)));
typedef __bf16 bf16x8 __attribute__((ext_vector_type(8)));
typedef float  f32x4  __attribute__((ext_vector_type(4)));

__device__ __forceinline__ void gload16(const void* g, void* l) {
  __builtin_amdgcn_global_load_lds(
      (const __attribute__((address_space(1))) void*)g,
      (__attribute__((address_space(3))) void*)l, 16, 0, 0);
}

// fast GELU (tanh form)
__device__ __forceinline__ float gelu_f(float v) {
  float u = v * v * v;
  float t = 1.5957691216f * v + 0.0713548162726f * u;
  float e = __expf(-t);
  return v * __builtin_amdgcn_rcpf(1.0f + e);
}

// ------------- fp32 [E][R][C] -> bf16 [E][C][R] tiled transpose -------------
__global__ void transpose_convert_kernel(const float* __restrict__ src,
                                         bf16* __restrict__ dst, int R, int C) {
  __shared__ bf16 tile[64][66];
  int e = blockIdx.z;
  src += (size_t)e * R * C;
  dst += (size_t)e * R * C;
  int c0 = blockIdx.x * 64;
  int r0 = blockIdx.y * 64;
  int lr = threadIdx.x >> 6;   // 0..3
  int lc = threadIdx.x & 63;
#pragma unroll
  for (int i = 0; i < 16; i++) {
    int r = lr + i * 4;
    tile[r][lc] = (bf16)src[(size_t)(r0 + r) * C + c0 + lc];
  }
  __syncthreads();
#pragma unroll
  for (int i = 0; i < 16; i++) {
    int r = lr + i * 4;  // row of dst block (= src col)
    dst[(size_t)(c0 + r) * R + r0 + lc] = tile[lc][r];
  }
}

// -- gating fused with x->bf16 convert: logits -> top2 -> softmax weights --
__global__ void gating_kernel(const float* __restrict__ x,
                              const float* __restrict__ gw,
                              const float* __restrict__ gb,
                              bf16* __restrict__ xb,
                              int* __restrict__ assignE,
                              float2* __restrict__ assignW) {
  int wave = threadIdx.x >> 6, lane = threadIdx.x & 63;
  int t = blockIdx.x * 4 + wave;
  const float* xr = x + (size_t)t * DM;
  // each lane owns 16 contiguous d: [lane*16, lane*16+16)
  float4 xv[4];
  const float4* xr4 = reinterpret_cast<const float4*>(xr) + lane * 4;
#pragma unroll
  for (int i = 0; i < 4; i++) xv[i] = xr4[i];
  // convert + store bf16 x
#pragma unroll
  for (int i = 0; i < 2; i++) {
    float4 a = xv[2 * i], b = xv[2 * i + 1];
    bf16x8 o;
    o[0] = (bf16)a.x; o[1] = (bf16)a.y; o[2] = (bf16)a.z; o[3] = (bf16)a.w;
    o[4] = (bf16)b.x; o[5] = (bf16)b.y; o[6] = (bf16)b.z; o[7] = (bf16)b.w;
    reinterpret_cast<bf16x8*>(xb + (size_t)t * DM)[lane * 2 + i] = o;
  }
  // gate logits
  float acc[8];
#pragma unroll
  for (int e = 0; e < 8; e++) acc[e] = 0.f;
  int d0 = lane * 16;
#pragma unroll
  for (int j = 0; j < 16; j++) {
    float xvj = reinterpret_cast<const float*>(xv)[j];
    const float4* g = reinterpret_cast<const float4*>(gw + (size_t)(d0 + j) * 8);
    float4 g0 = g[0], g1 = g[1];
    acc[0] += xvj * g0.x; acc[1] += xvj * g0.y; acc[2] += xvj * g0.z; acc[3] += xvj * g0.w;
    acc[4] += xvj * g1.x; acc[5] += xvj * g1.y; acc[6] += xvj * g1.z; acc[7] += xvj * g1.w;
  }
#pragma unroll
  for (int off = 32; off > 0; off >>= 1)
#pragma unroll
    for (int e = 0; e < 8; e++) acc[e] += __shfl_xor(acc[e], off, 64);
  if (lane == 0) {
    float v[8];
#pragma unroll
    for (int e = 0; e < 8; e++) v[e] = acc[e] + gb[e];
    int i0 = 0; float v0 = v[0];
#pragma unroll
    for (int e = 1; e < 8; e++) if (v[e] > v0) { v0 = v[e]; i0 = e; }
    int i1 = -1; float v1 = -1e30f;
#pragma unroll
    for (int e = 0; e < 8; e++) if (e != i0 && v[e] > v1) { v1 = v[e]; i1 = e; }
    float p1 = expf(v1 - v0);
    float den = 1.f + p1;
    assignE[t] = i0 | (i1 << 8);
    assignW[t] = make_float2(1.f / den, p1 / den);
  }
}

// ---- router (single block, 512 thr): histogram -> offsets -> LUT -> scatter ----
__global__ void router_kernel(const int* __restrict__ assignE,
                              const float2* __restrict__ assignW,
                              int* __restrict__ rowTok,
                              float* __restrict__ rowW,
                              int2* __restrict__ tokRow,
                              int* __restrict__ tileExpert) {
  __shared__ int cnt[NE], off[NE + 1], cur[NE];
  int tid = threadIdx.x;
  if (tid < NE) cnt[tid] = 0;
  __syncthreads();
  for (int t = tid; t < NTOK; t += 512) {
    int ae = assignE[t];
    atomicAdd(&cnt[ae & 255], 1);
    atomicAdd(&cnt[(ae >> 8) & 255], 1);
  }
  __syncthreads();
  if (tid == 0) {
    int o = 0;
    for (int e = 0; e < NE; e++) { off[e] = o; o += ((cnt[e] + 127) >> 7) << 7; }
    off[NE] = o;
  }
  __syncthreads();
  if (tid < NE) cur[tid] = 0;
  for (int i = tid; i < CAPT; i += 512) {
    int r = i * 128, ex = -1;
#pragma unroll
    for (int e = 0; e < NE; e++)
      if (r >= off[e] && r < off[e + 1]) ex = e;
    tileExpert[i] = ex;
  }
  for (int i = tid; i < CAP; i += 512) { rowTok[i] = -1; rowW[i] = 0.f; }
  __syncthreads();
  for (int t = tid; t < NTOK; t += 512) {
    int ae = assignE[t];
    float2 aw = assignW[t];
    int e0 = ae & 255, e1 = (ae >> 8) & 255;
    int p0 = off[e0] + atomicAdd(&cur[e0], 1);
    rowTok[p0] = t; rowW[p0] = aw.x;
    int p1 = off[e1] + atomicAdd(&cur[e1], 1);
    rowTok[p1] = t; rowW[p1] = aw.y;
    tokRow[t] = make_int2(p0, p1);
  }
}

// ---------------- grouped bf16 MFMA GEMM over expert segments ----------------
// 2-phase double-buffered K-loop (r6 verified ledger), BK=32 for occupancy:
// LDS 32 KB -> 4 blocks/CU, 16 waves/CU (2x TLP vs BK=64).
// Swizzle for 64B rows: col ^= (row&3)<<4, write-side via pre-swizzled global
// source (rule #21), read-side same XOR.
// EPI==0: A gathered via rowTok; Hout[r,n] = gelu(C + bias[n])  (bf16)
// EPI==1: A direct; Y[r][n] = rowW[r] * (C + bias[n])  (fp32, linear)
template <int EPI>
__global__ __launch_bounds__(256) void moe_gemm_kernel(
    const bf16* __restrict__ A, const bf16* __restrict__ Bt,
    const float* __restrict__ bias, bf16* __restrict__ Hout,
    float* __restrict__ Y,
    const int* __restrict__ rowTok, const float* __restrict__ rowW,
    const int* __restrict__ tileExpert,
    int N, int K) {
  constexpr int BM = 128, BN = 128, BK = 32;
  __shared__ __align__(16) bf16 As0[BM * BK];
  __shared__ __align__(16) bf16 Bs0[BN * BK];
  __shared__ __align__(16) bf16 As1[BM * BK];
  __shared__ __align__(16) bf16 Bs1[BN * BK];
  const int tid = threadIdx.x;
  const int wave = tid >> 6, lane = tid & 63;
  const int nbn = N / BN;
  const int bid = (int)blockIdx.x;
  // natural order: XCD = bid % 8 = fixed column stripe -> B-panel L2 affinity
  const int rt = bid / nbn;
  const int e = tileExpert[rt];
  if (e < 0) return;
  const int bm0 = rt * BM;
  const int bn0 = (bid % nbn) * BN;
  const int wm = (wave >> 1) * 64, wn = (wave & 1) * 64;
  const bf16* Be = Bt + (size_t)e * N * K;
  const float* be = bias + (size_t)e * N;

  f32x4 acc[4][4];
#pragma unroll
  for (int m = 0; m < 4; m++)
#pragma unroll
    for (int n = 0; n < 4; n++)
#pragma unroll
      for (int j = 0; j < 4; j++) acc[m][n][j] = 0.f;

  // staging geometry (BK=32, 64B rows): one wave-gload covers 16 rows.
  // chunk = it*4 + wave (it=0..1) -> rows chunk*16 + (lane>>2), 16B slot lane&3.
  const int srow = lane >> 2;            // 0..15 within a 16-row chunk
  const int scolb = (lane & 3) << 4;     // byte col 0..48

  // hoist per-thread row base pointers (rows fixed across K-loop)
  const char* gaBase[2];
  const char* gbBase[2];
#pragma unroll
  for (int it = 0; it < 2; it++) {
    int chunk = it * 4 + wave;
    int row = chunk * 16 + srow;
    int csw = scolb ^ ((row & 3) << 4);  // pre-swizzled source (rule #21)
    size_t arow;
    if constexpr (EPI == 0) {
      int tok = rowTok[bm0 + row];
      arow = (size_t)(tok < 0 ? 0 : tok);
    } else {
      arow = (size_t)(bm0 + row);
    }
    gaBase[it] = (const char*)A + arow * (size_t)K * 2 + csw;
    gbBase[it] = (const char*)Be + ((size_t)(bn0 + row)) * K * 2 + csw;
  }

  auto STAGE = [&](int kt, bf16* dstA, bf16* dstB) {
#pragma unroll
    for (int it = 0; it < 2; it++) {
      int chunk = it * 4 + wave;
      gload16(gaBase[it] + (size_t)kt * 2, (char*)dstA + chunk * 1024);
      gload16(gbBase[it] + (size_t)kt * 2, (char*)dstB + chunk * 1024);
    }
  };

  auto COMPUTE = [&](const bf16* sA, const bf16* sB) {
    const int kb = (lane >> 4) << 4;     // 16B k-slot within 64B row
    bf16x8 af[4], bfv[4];
#pragma unroll
    for (int m = 0; m < 4; m++) {
      int r = wm + m * 16 + (lane & 15);
      af[m] = *(const bf16x8*)((const char*)sA + r * 64 + (kb ^ ((r & 3) << 4)));
    }
#pragma unroll
    for (int n = 0; n < 4; n++) {
      int r = wn + n * 16 + (lane & 15);
      bfv[n] = *(const bf16x8*)((const char*)sB + r * 64 + (kb ^ ((r & 3) << 4)));
    }
#pragma unroll
    for (int m = 0; m < 4; m++)
#pragma unroll
      for (int n = 0; n < 4; n++)
        acc[m][n] = __builtin_amdgcn_mfma_f32_16x16x32_bf16(af[m], bfv[n], acc[m][n], 0, 0, 0);
  };

  // prologue: fill buffer 0
  STAGE(0, As0, Bs0);
  __syncthreads();                       // vmcnt(0) + barrier: buf0 ready
  // main loop: 2 K-steps per iteration, static buffer references
  for (int kt = 0; kt < K; kt += 2 * BK) {
    if (kt + BK < K) STAGE(kt + BK, As1, Bs1);   // prefetch into buf1
    COMPUTE(As0, Bs0);
    __syncthreads();                     // buf1 ready; buf0 reads done
    if (kt + 2 * BK < K) STAGE(kt + 2 * BK, As0, Bs0);  // prefetch into buf0
    COMPUTE(As1, Bs1);
    __syncthreads();                     // buf0 ready; buf1 reads done
  }

  const int rb = bm0 + wm + ((lane >> 4) << 2);
  const int cb = bn0 + wn + (lane & 15);
  if constexpr (EPI == 0) {
#pragma unroll
    for (int m = 0; m < 4; m++)
#pragma unroll
      for (int n = 0; n < 4; n++) {
        int c = cb + n * 16;
        float bv = be[c];
#pragma unroll
        for (int j = 0; j < 4; j++) {
          int r = rb + m * 16 + j;
          Hout[(size_t)r * N + c] = (bf16)gelu_f(acc[m][n][j] + bv);
        }
      }
  } else {
#pragma unroll
    for (int m = 0; m < 4; m++) {
#pragma unroll
      for (int j = 0; j < 4; j++) {
        int r = rb + m * 16 + j;
        float w = rowW[r];
        float* yrow = Y + (size_t)r * DM;
#pragma unroll
        for (int n = 0; n < 4; n++) {
          int c = cb + n * 16;
          yrow[c] = w * (acc[m][n][j] + be[c]);
        }
      }
    }
  }
}

// ---------------- combine: out[t] = Y[p0] + Y[p1] ----------------
__global__ void combine_kernel(const float* __restrict__ Y,
                               const int2* __restrict__ tokRow,
                               float* __restrict__ out) {
  int wave = threadIdx.x >> 6, lane = threadIdx.x & 63;
  int t = blockIdx.x * 4 + wave;
  int2 pr = tokRow[t];
  const float4* a = (const float4*)(Y + (size_t)pr.x * DM);
  const float4* b = (const float4*)(Y + (size_t)pr.y * DM);
  float4* o = (float4*)(out + (size_t)t * DM);
#pragma unroll
  for (int i = 0; i < 4; i++) {
    int idx = lane + i * 64;
    float4 u = a[idx], v = b[idx];
    o[idx] = make_float4(u.x + v.x, u.y + v.y, u.z + v.z, u.w + v.w);
  }
}

extern "C" void kernel_launch(void* const* d_in, const int* in_sizes, int n_in,
                              void* d_out, int out_size, void* d_ws, size_t ws_size,
                              hipStream_t stream) {
  const float* x  = (const float*)d_in[0];
  const float* gw = (const float*)d_in[1];
  const float* gb = (const float*)d_in[2];
  const float* w1 = (const float*)d_in[3];
  const float* b1 = (const float*)d_in[4];
  const float* w2 = (const float*)d_in[5];
  const float* b2 = (const float*)d_in[6];
  float* out = (float*)d_out;

  char* p = (char*)d_ws;
  bf16* xb   = (bf16*)p;  p += (size_t)NTOK * DM * 2;      // 16.8 MB (dead after GEMM1)
  bf16* w1t  = (bf16*)p;  p += (size_t)NE * DM * DH * 2;   // 67 MB   (dead after GEMM1)
  bf16* Hg   = (bf16*)p;  p += (size_t)CAP * DH * 2;       // 142.6 MB
  bf16* w2t  = (bf16*)p;  p += (size_t)NE * DM * DH * 2;   // 67 MB  [E][D][H]
  int*   assignE = (int*)p;     p += (size_t)NTOK * 4;
  float2* assignW = (float2*)p; p += (size_t)NTOK * 8;
  int*   rowTok = (int*)p;      p += (size_t)CAP * 4;
  float* rowW   = (float*)p;    p += (size_t)CAP * 4;
  int2*  tokRow = (int2*)p;     p += (size_t)NTOK * 8;
  int*   tileExpert = (int*)p;  p += (size_t)CAPT * 4;
  // Y aliases xb+w1t (71.3 MB <= 83.8 MB; both dead once GEMM2 runs)
  float* Y = (float*)d_ws;

  // w1 [E][DM][DH] -> w1t [E][DH][DM]
  transpose_convert_kernel<<<dim3(DH / 64, DM / 64, NE), 256, 0, stream>>>(w1, w1t, DM, DH);
  // w2 [E][DH][DM] -> w2t [E][DM][DH]
  transpose_convert_kernel<<<dim3(DM / 64, DH / 64, NE), 256, 0, stream>>>(w2, w2t, DH, DM);
  gating_kernel<<<NTOK / 4, 256, 0, stream>>>(x, gw, gb, xb, assignE, assignW);
  router_kernel<<<1, 512, 0, stream>>>(assignE, assignW, rowTok, rowW, tokRow, tileExpert);

  // GEMM1: gathered x @ w1^T -> gelu -> Hg   [CAP x DH]
  moe_gemm_kernel<0><<<CAPT * (DH / 128), 256, 0, stream>>>(
      xb, w1t, b1, Hg, nullptr, rowTok, nullptr, tileExpert, DH, DM);
  // GEMM2: Hg @ w2^T -> Y[r] = w*(y+b2)  (linear, gathered-row space)
  moe_gemm_kernel<1><<<CAPT * (DM / 128), 256, 0, stream>>>(
      Hg, w2t, b2, nullptr, Y, rowTok, rowW, tileExpert, DM, DH);

  combine_kernel<<<NTOK / 4, 256, 0, stream>>>(Y, tokRow, out);
}